// Round 10
// baseline (41.937 us; speedup 1.0000x reference)
//
#include <hip/hip_runtime.h>

// DilateAttention: q,k,v [B=16, d=32, H=128, W=128] fp32, kernel=3, dilation=2, pad=2.
// Per-pixel 1x9 attention over dilated 3x3 window; OOB taps are zero-padded
// (score 0, value 0) and participate in the softmax denominator.
//
// R10: R9's economy + 4x wave-level parallelism (the one lever never pulled;
// all 9 prior rounds were wait-bound at 2-4 waves/SIMD).
//  - Block = 4 waves on the SAME (b,h) row, each owning a d-quarter (8 d's)
//    -> loads stay single-segment 512B float2 (wave-level d-split, unlike the
//    R6/R7 lane-level splits that doubled line traffic).
//  - Pass-1 partial cross-products reduced across the 4 waves via one LDS
//    exchange (18 KB, b64 conflict-free) + ONE barrier. Each wave then
//    redundantly runs the cheap softmax and does Pass 2 for its own 8 d's
//    (outputs are per-d: no second reduction).
//  - Grid 2048 blocks -> 8 blocks/CU x 4 waves = 32 waves/CU = 8/SIMD.
// Kept from R9 (verified): shifted-q cross-products, pre-shifted PV weights,
// clamped unpredicated loads + validity cancellation, XCD-chunk swizzle.

#define BB 16
#define HD 32
#define HH 128
#define WW 128
#define PLANE (HH * WW)
#define CHUNK 2
#define DQ 8          // d's per wave

__global__ __launch_bounds__(256, 6) void dilate_attn_kernel(
    const float* __restrict__ q,
    const float* __restrict__ k,
    const float* __restrict__ v,
    float* __restrict__ out)
{
    // red[kind_r][wave][lane][px]: kind_r = r*3+kind (9), 4 waves, 64 lanes, 2 px
    __shared__ float red[9 * 512];   // 18 KB

    const int tid  = threadIdx.x;
    const int wv   = tid >> 6;         // wave 0..3 = d-quarter
    const int lane = tid & 63;
    const int w2   = lane * 2;         // px pair (w2, w2+1)

    const int bid   = blockIdx.x;                    // 0..2047
    const int rowid = (bid & 7) * 256 + (bid >> 3);  // XCD-chunk swizzle
    const int h = rowid & (HH - 1);
    const int b = rowid >> 7;

    const size_t dbase = ((size_t)b * HD + (size_t)wv * DQ) * PLANE + (size_t)h * WW;

    // Row validity (wave-uniform) and clamped row offsets.
    const bool hlo = (h >= 2), hhi = (h <= HH - 3);
    const int  roff[3] = { hlo ? -2 * WW : 0, 0, hhi ? 2 * WW : 0 };
    const bool rv[3]   = { hlo, true, hhi };

    // Column validity (uniform for the px pair).
    const bool tvlo = (lane >= 1), tvhi = (lane <= 62);

    // Clamped shifted-q columns (even -> float2-aligned; garbage cancelled).
    const int cql = tvlo ? w2 - 2 : 0;
    const int cqh = tvhi ? w2 + 2 : w2;

    const int im1 = (lane + 63) & 63;
    const int ip1 = (lane + 1) & 63;

    // ---- Pass 1: cross-products over this wave's 8 d's ----
    // P[r][kind][px]; kind 0=lo (q_hi*k), 1=ce (q_ce*k), 2=hi (q_lo*k)
    float P[3][3][2];
    #pragma unroll
    for (int r = 0; r < 3; ++r)
        #pragma unroll
        for (int kd = 0; kd < 3; ++kd) { P[r][kd][0] = 0.f; P[r][kd][1] = 0.f; }

    const float* qrow = q + dbase;
    const float* krow = k + dbase;

    for (int c = 0; c < DQ; c += CHUNK) {
        float2 ql[CHUNK], qc[CHUNK], qh[CHUNK], kr[CHUNK][3];
        #pragma unroll
        for (int u = 0; u < CHUNK; ++u) {
            const size_t dp = (size_t)(c + u) * PLANE;
            ql[u] = *(const float2*)(qrow + dp + cql);
            qc[u] = *(const float2*)(qrow + dp + w2);
            qh[u] = *(const float2*)(qrow + dp + cqh);
            #pragma unroll
            for (int r = 0; r < 3; ++r)
                kr[u][r] = *(const float2*)(krow + dp + roff[r] + w2);
        }
        #pragma unroll
        for (int u = 0; u < CHUNK; ++u) {
            #pragma unroll
            for (int r = 0; r < 3; ++r) {
                P[r][0][0] = fmaf(qh[u].x, kr[u][r].x, P[r][0][0]);
                P[r][0][1] = fmaf(qh[u].y, kr[u][r].y, P[r][0][1]);
                P[r][1][0] = fmaf(qc[u].x, kr[u][r].x, P[r][1][0]);
                P[r][1][1] = fmaf(qc[u].y, kr[u][r].y, P[r][1][1]);
                P[r][2][0] = fmaf(ql[u].x, kr[u][r].x, P[r][2][0]);
                P[r][2][1] = fmaf(ql[u].y, kr[u][r].y, P[r][2][1]);
            }
        }
    }

    // ---- Cross-wave reduction of partials (one barrier) ----
    #pragma unroll
    for (int r = 0; r < 3; ++r)
        #pragma unroll
        for (int kd = 0; kd < 3; ++kd)
            *(float2*)&red[(r * 3 + kd) * 512 + wv * 128 + w2] =
                make_float2(P[r][kd][0], P[r][kd][1]);
    __syncthreads();

    float S[3][3][2];
    #pragma unroll
    for (int r = 0; r < 3; ++r) {
        #pragma unroll
        for (int kd = 0; kd < 3; ++kd) {
            float ax = 0.f, ay = 0.f;
            #pragma unroll
            for (int w4 = 0; w4 < 4; ++w4) {
                const float2 t = *(const float2*)&red[(r * 3 + kd) * 512 + w4 * 128 + w2];
                ax += t.x; ay += t.y;
            }
            S[r][kd][0] = ax; S[r][kd][1] = ay;
        }
    }

    // ---- Recover the 9 scores per pixel (shuffles; wrap garbage cancelled) ----
    float s0[9], s1[9];
    #pragma unroll
    for (int r = 0; r < 3; ++r) {
        const float a0 = __shfl(S[r][0][0], im1), a1 = __shfl(S[r][0][1], im1);
        const float b0 = __shfl(S[r][2][0], ip1), b1 = __shfl(S[r][2][1], ip1);
        const bool vlo = rv[r] && tvlo, vhi = rv[r] && tvhi;
        s0[r * 3 + 0] = vlo ? a0 : 0.f;         s1[r * 3 + 0] = vlo ? a1 : 0.f;
        s0[r * 3 + 1] = rv[r] ? S[r][1][0] : 0.f; s1[r * 3 + 1] = rv[r] ? S[r][1][1] : 0.f;
        s0[r * 3 + 2] = vhi ? b0 : 0.f;         s1[r * 3 + 2] = vhi ? b1 : 0.f;
    }

    // ---- Softmax over 9 taps per pixel (invalid taps enter as score 0) ----
    const float scale = 0.17677669529663687f;  // 32^-0.5
    {
        float m0 = -3.4e38f, m1 = -3.4e38f;
        #pragma unroll
        for (int n = 0; n < 9; ++n) {
            s0[n] *= scale; m0 = fmaxf(m0, s0[n]);
            s1[n] *= scale; m1 = fmaxf(m1, s1[n]);
        }
        float sum0 = 0.f, sum1 = 0.f;
        #pragma unroll
        for (int n = 0; n < 9; ++n) {
            s0[n] = __expf(s0[n] - m0); sum0 += s0[n];
            s1[n] = __expf(s1[n] - m1); sum1 += s1[n];
        }
        const float i0 = 1.f / sum0, i1 = 1.f / sum1;
        #pragma unroll
        for (int n = 0; n < 9; ++n) { s0[n] *= i0; s1[n] *= i1; }
    }

    // Zero weights of invalid taps (reference v is zero-padded there).
    #pragma unroll
    for (int r = 0; r < 3; ++r) {
        const bool vlo = rv[r] && tvlo, vhi = rv[r] && tvhi;
        if (!vlo)   { s0[r * 3 + 0] = 0.f; s1[r * 3 + 0] = 0.f; }
        if (!rv[r]) { s0[r * 3 + 1] = 0.f; s1[r * 3 + 1] = 0.f; }
        if (!vhi)   { s0[r * 3 + 2] = 0.f; s1[r * 3 + 2] = 0.f; }
    }

    // ---- Pre-shift weights for pass 2 (zeroed at wrap) ----
    float wl0[3], wl1[3], wh0[3], wh1[3], wc0[3], wc1[3];
    #pragma unroll
    for (int r = 0; r < 3; ++r) {
        const float a0 = __shfl(s0[r * 3 + 0], ip1), a1 = __shfl(s1[r * 3 + 0], ip1);
        const float b0 = __shfl(s0[r * 3 + 2], im1), b1 = __shfl(s1[r * 3 + 2], im1);
        wl0[r] = tvhi ? a0 : 0.f;  wl1[r] = tvhi ? a1 : 0.f;  // lane 63 -> 0
        wh0[r] = tvlo ? b0 : 0.f;  wh1[r] = tvlo ? b1 : 0.f;  // lane 0  -> 0
        wc0[r] = s0[r * 3 + 1];    wc1[r] = s1[r * 3 + 1];
    }

    // ---- Pass 2: PV for this wave's 8 d's ----
    const float* vrow = v + dbase;
    float*       orow = out + dbase;

    for (int c = 0; c < DQ; c += CHUNK) {
        float2 vr[CHUNK][3];
        #pragma unroll
        for (int u = 0; u < CHUNK; ++u) {
            const size_t dp = (size_t)(c + u) * PLANE;
            #pragma unroll
            for (int r = 0; r < 3; ++r)
                vr[u][r] = *(const float2*)(vrow + dp + roff[r] + w2);
        }
        #pragma unroll
        for (int u = 0; u < CHUNK; ++u) {
            float tl0 = 0.f, tl1 = 0.f, tc0 = 0.f, tc1 = 0.f, th0 = 0.f, th1 = 0.f;
            #pragma unroll
            for (int r = 0; r < 3; ++r) {
                tl0 = fmaf(wl0[r], vr[u][r].x, tl0);
                tl1 = fmaf(wl1[r], vr[u][r].y, tl1);
                tc0 = fmaf(wc0[r], vr[u][r].x, tc0);
                tc1 = fmaf(wc1[r], vr[u][r].y, tc1);
                th0 = fmaf(wh0[r], vr[u][r].x, th0);
                th1 = fmaf(wh1[r], vr[u][r].y, th1);
            }
            // out[px] = t_ce + t_lo(from lane-1) + t_hi(from lane+1)
            const float rl0 = __shfl(tl0, im1), rl1 = __shfl(tl1, im1);
            const float rh0 = __shfl(th0, ip1), rh1 = __shfl(th1, ip1);
            *(float2*)(orow + (size_t)(c + u) * PLANE + w2) =
                make_float2(tc0 + rl0 + rh0, tc1 + rl1 + rh1);
        }
    }
}

extern "C" void kernel_launch(void* const* d_in, const int* in_sizes, int n_in,
                              void* d_out, int out_size, void* d_ws, size_t ws_size,
                              hipStream_t stream) {
    const float* q = (const float*)d_in[0];
    const float* k = (const float*)d_in[1];
    const float* v = (const float*)d_in[2];
    float* out = (float*)d_out;

    dim3 grid(BB * HH);   // 2048 blocks, one (b,h) row each
    dim3 block(256);      // 4 waves = 4 d-quarters of the same row
    dilate_attn_kernel<<<grid, block, 0, stream>>>(q, k, v, out);
}

// Round 11
// 38.126 us; speedup vs baseline: 1.1000x; 1.1000x over previous
//
#include <hip/hip_runtime.h>

// DilateAttention: q,k,v [B=16, d=32, H=128, W=128] fp32, kernel=3, dilation=2, pad=2.
// Per-pixel 1x9 attention over dilated 3x3 window; OOB taps are zero-padded
// (score 0, value 0) and participate in the softmax denominator.
//
// R11: R9's verified per-wave economy (cross-product shifted-q pass 1,
// pre-shifted-weight pass 2, float2 lanes, wave = one full 128-px row,
// clamp+cancel edges, no lane-level d-split) RE-BLOCKED for tap-row dedup:
//  - Block = 8 waves = 8 CONSECUTIVE rows (one strip), grid 256 = 1 block/CU.
//    Per d the block needs 12 unique k rows for 8 output rows (1.5x/row)
//    instead of 3x/row across scattered blocks -> L2-side traffic
//    ~230 MB -> ~167 MB if L1/L2 dedups same-row requests.
//  - __syncthreads() after every CHUNK=4 d-chunk keeps the 8 waves marching
//    through d together (chunk footprint ~24-40 KB ~ L1; L2 catches drift).
//  - XCD swizzle (bid&7)*32+(bid>>3): 32 consecutive strips per XCD.

#define BB 16
#define HD 32
#define HH 128
#define WW 128
#define PLANE (HH * WW)
#define CHUNK 4

__global__ __launch_bounds__(512, 1) void dilate_attn_kernel(
    const float* __restrict__ q,
    const float* __restrict__ k,
    const float* __restrict__ v,
    float* __restrict__ out)
{
    const int tid  = threadIdx.x;
    const int wv   = tid >> 6;         // wave 0..7 = row within strip
    const int lane = tid & 63;
    const int w2   = lane * 2;         // px pair (w2, w2+1)

    const int bid   = blockIdx.x;                   // 0..255
    const int strip = (bid & 7) * 32 + (bid >> 3);  // XCD-chunk swizzle
    const int rowid = strip * 8 + wv;               // 0..2047
    const int h = rowid & (HH - 1);
    const int b = rowid >> 7;

    const size_t base = (size_t)b * HD * PLANE + (size_t)h * WW;

    // Row validity (wave-uniform) and clamped row offsets.
    const bool hlo = (h >= 2), hhi = (h <= HH - 3);
    const int  roff[3] = { hlo ? -2 * WW : 0, 0, hhi ? 2 * WW : 0 };
    const bool rv[3]   = { hlo, true, hhi };

    // Column validity (uniform for the px pair).
    const bool tvlo = (lane >= 1), tvhi = (lane <= 62);

    // Clamped shifted-q columns (even -> float2-aligned; garbage cancelled).
    const int cql = tvlo ? w2 - 2 : 0;
    const int cqh = tvhi ? w2 + 2 : w2;

    const int im1 = (lane + 63) & 63;
    const int ip1 = (lane + 1) & 63;

    // ---- Pass 1: cross-products over d (6 float2 loads/d) ----
    float Plo0[3] = {0,0,0}, Plo1[3] = {0,0,0};   // -> s_lo of px+2 (lane+1)
    float Pce0[3] = {0,0,0}, Pce1[3] = {0,0,0};   // -> s_ce of px   (lane)
    float Phi0[3] = {0,0,0}, Phi1[3] = {0,0,0};   // -> s_hi of px-2 (lane-1)

    const float* qrow = q + base;
    const float* krow = k + base;

    for (int c = 0; c < HD; c += CHUNK) {
        float2 ql[CHUNK], qc[CHUNK], qh[CHUNK], kr[CHUNK][3];
        #pragma unroll
        for (int u = 0; u < CHUNK; ++u) {
            const size_t dp = (size_t)(c + u) * PLANE;
            ql[u] = *(const float2*)(qrow + dp + cql);
            qc[u] = *(const float2*)(qrow + dp + w2);
            qh[u] = *(const float2*)(qrow + dp + cqh);
            #pragma unroll
            for (int r = 0; r < 3; ++r)
                kr[u][r] = *(const float2*)(krow + dp + roff[r] + w2);
        }
        #pragma unroll
        for (int u = 0; u < CHUNK; ++u) {
            #pragma unroll
            for (int r = 0; r < 3; ++r) {
                Plo0[r] = fmaf(qh[u].x, kr[u][r].x, Plo0[r]);
                Plo1[r] = fmaf(qh[u].y, kr[u][r].y, Plo1[r]);
                Pce0[r] = fmaf(qc[u].x, kr[u][r].x, Pce0[r]);
                Pce1[r] = fmaf(qc[u].y, kr[u][r].y, Pce1[r]);
                Phi0[r] = fmaf(ql[u].x, kr[u][r].x, Phi0[r]);
                Phi1[r] = fmaf(ql[u].y, kr[u][r].y, Phi1[r]);
            }
        }
        __syncthreads();   // keep the strip's 8 waves marching together
    }

    // ---- Recover scores: s_lo[px]=P_lo[lane-1], s_hi[px]=P_hi[lane+1] ----
    float s0[9], s1[9];
    #pragma unroll
    for (int r = 0; r < 3; ++r) {
        const float a0 = __shfl(Plo0[r], im1), a1 = __shfl(Plo1[r], im1);
        const float b0 = __shfl(Phi0[r], ip1), b1 = __shfl(Phi1[r], ip1);
        const bool vlo = rv[r] && tvlo, vhi = rv[r] && tvhi;
        s0[r * 3 + 0] = vlo ? a0 : 0.f;           s1[r * 3 + 0] = vlo ? a1 : 0.f;
        s0[r * 3 + 1] = rv[r] ? Pce0[r] : 0.f;    s1[r * 3 + 1] = rv[r] ? Pce1[r] : 0.f;
        s0[r * 3 + 2] = vhi ? b0 : 0.f;           s1[r * 3 + 2] = vhi ? b1 : 0.f;
    }

    // ---- Softmax over 9 taps per pixel (invalid taps enter as score 0) ----
    const float scale = 0.17677669529663687f;  // 32^-0.5
    {
        float m0 = -3.4e38f, m1 = -3.4e38f;
        #pragma unroll
        for (int n = 0; n < 9; ++n) {
            s0[n] *= scale; m0 = fmaxf(m0, s0[n]);
            s1[n] *= scale; m1 = fmaxf(m1, s1[n]);
        }
        float sum0 = 0.f, sum1 = 0.f;
        #pragma unroll
        for (int n = 0; n < 9; ++n) {
            s0[n] = __expf(s0[n] - m0); sum0 += s0[n];
            s1[n] = __expf(s1[n] - m1); sum1 += s1[n];
        }
        const float i0 = 1.f / sum0, i1 = 1.f / sum1;
        #pragma unroll
        for (int n = 0; n < 9; ++n) { s0[n] *= i0; s1[n] *= i1; }
    }

    // Zero weights of invalid taps (reference v is zero-padded there).
    #pragma unroll
    for (int r = 0; r < 3; ++r) {
        const bool vlo = rv[r] && tvlo, vhi = rv[r] && tvhi;
        if (!vlo)   { s0[r * 3 + 0] = 0.f; s1[r * 3 + 0] = 0.f; }
        if (!rv[r]) { s0[r * 3 + 1] = 0.f; s1[r * 3 + 1] = 0.f; }
        if (!vhi)   { s0[r * 3 + 2] = 0.f; s1[r * 3 + 2] = 0.f; }
    }

    // ---- Pre-shift weights for pass 2 (zeroed at wrap) ----
    float wl0[3], wl1[3], wh0[3], wh1[3], wc0[3], wc1[3];
    #pragma unroll
    for (int r = 0; r < 3; ++r) {
        const float a0 = __shfl(s0[r * 3 + 0], ip1), a1 = __shfl(s1[r * 3 + 0], ip1);
        const float b0 = __shfl(s0[r * 3 + 2], im1), b1 = __shfl(s1[r * 3 + 2], im1);
        wl0[r] = tvhi ? a0 : 0.f;  wl1[r] = tvhi ? a1 : 0.f;  // lane 63 -> 0
        wh0[r] = tvlo ? b0 : 0.f;  wh1[r] = tvlo ? b1 : 0.f;  // lane 0  -> 0
        wc0[r] = s0[r * 3 + 1];    wc1[r] = s1[r * 3 + 1];
    }

    // ---- Pass 2: PV with 3 v loads + 1 store + 4 shuffles per d ----
    const float* vrow = v + base;
    float*       orow = out + base;

    for (int c = 0; c < HD; c += CHUNK) {
        float2 vr[CHUNK][3];
        #pragma unroll
        for (int u = 0; u < CHUNK; ++u) {
            const size_t dp = (size_t)(c + u) * PLANE;
            #pragma unroll
            for (int r = 0; r < 3; ++r)
                vr[u][r] = *(const float2*)(vrow + dp + roff[r] + w2);
        }
        #pragma unroll
        for (int u = 0; u < CHUNK; ++u) {
            float tl0 = 0.f, tl1 = 0.f, tc0 = 0.f, tc1 = 0.f, th0 = 0.f, th1 = 0.f;
            #pragma unroll
            for (int r = 0; r < 3; ++r) {
                tl0 = fmaf(wl0[r], vr[u][r].x, tl0);
                tl1 = fmaf(wl1[r], vr[u][r].y, tl1);
                tc0 = fmaf(wc0[r], vr[u][r].x, tc0);
                tc1 = fmaf(wc1[r], vr[u][r].y, tc1);
                th0 = fmaf(wh0[r], vr[u][r].x, th0);
                th1 = fmaf(wh1[r], vr[u][r].y, th1);
            }
            // out[px] = t_ce + t_lo(from lane-1) + t_hi(from lane+1)
            const float rl0 = __shfl(tl0, im1), rl1 = __shfl(tl1, im1);
            const float rh0 = __shfl(th0, ip1), rh1 = __shfl(th1, ip1);
            *(float2*)(orow + (size_t)(c + u) * PLANE + w2) =
                make_float2(tc0 + rl0 + rh0, tc1 + rl1 + rh1);
        }
        __syncthreads();   // lockstep for v-row dedup
    }
}

extern "C" void kernel_launch(void* const* d_in, const int* in_sizes, int n_in,
                              void* d_out, int out_size, void* d_ws, size_t ws_size,
                              hipStream_t stream) {
    const float* q = (const float*)d_in[0];
    const float* k = (const float*)d_in[1];
    const float* v = (const float*)d_in[2];
    float* out = (float*)d_out;

    dim3 grid(BB * HH / 8);  // 256 blocks = 8-row strips, 1 per CU
    dim3 block(512);         // 8 waves; wave = one full row
    dilate_attn_kernel<<<grid, block, 0, stream>>>(q, k, v, out);
}

// Round 12
// 33.850 us; speedup vs baseline: 1.2389x; 1.1263x over previous
//
#include <hip/hip_runtime.h>

// DilateAttention: q,k,v [B=16, d=32, H=128, W=128] fp32, kernel=3, dilation=2, pad=2.
// Per-pixel 1x9 attention over dilated 3x3 window; OOB taps are zero-padded
// (score 0, value 0) and participate in the softmax denominator.
//
// R12 = R4 (best simple kernel, 34.3 us) + ONE change: nontemporal stores for
// `out`. Theory: out's 33.5 MB write-allocates in L3 every replay, evicting
// inputs -> the constant 49 MB HBM FETCH whose cold-miss latency is the
// structure-invariant ~34 us floor. Nontemporal stores bypass L3 allocation,
// keeping q/k/v fully L3-resident. Everything else is byte-identical to R4:
// phase-split register load batches (~40 in flight), clamped unpredicated
// loads + tv[] cancellation, XCD-chunk swizzle.

#define BB 16
#define HD 32
#define HH 128
#define WW 128
#define PLANE (HH * WW)
#define CHUNK 4

__global__ __launch_bounds__(128) void dilate_attn_kernel(
    const float* __restrict__ q,
    const float* __restrict__ k,
    const float* __restrict__ v,
    float* __restrict__ out)
{
    const int w   = threadIdx.x;          // 0..127
    const int bid = blockIdx.x;           // 0..2047
    // XCD swizzle: 2048 blocks / 8 XCDs -> XCD x owns rowids [x*256,(x+1)*256)
    const int rowid = (bid & 7) * 256 + (bid >> 3);
    const int h = rowid & (HH - 1);
    const int b = rowid >> 7;

    const size_t base = ((size_t)b * HD) * PLANE + (size_t)h * WW + w;

    // Clamped tap offsets (always in-bounds). Garbage cancelled after pass 1.
    const int  dlo = (w >= 2)      ? -2      : -w;
    const int  dhi = (w <= WW - 3) ?  2      : (WW - 1 - w);
    const int  rlo = (h >= 2)      ? -2 * WW : 0;   // wave-uniform
    const int  rhi = (h <= HH - 3) ?  2 * WW : 0;   // wave-uniform
    const bool wlo = (w >= 2), whi = (w <= WW - 3);
    const bool hlo = (h >= 2), hhi = (h <= HH - 3);

    int off[9];
    off[0] = rlo + dlo; off[1] = rlo; off[2] = rlo + dhi;
    off[3] = dlo;       off[4] = 0;   off[5] = dhi;
    off[6] = rhi + dlo; off[7] = rhi; off[8] = rhi + dhi;

    const bool tv[9] = { hlo && wlo, hlo, hlo && whi,
                         wlo,        true, whi,
                         hhi && wlo, hhi, hhi && whi };

    // ---- Pass 1: scores. Per 4-d chunk: 40 loads into regs, THEN 36 FMAs ----
    float s[9];
    #pragma unroll
    for (int n = 0; n < 9; ++n) s[n] = 0.f;

    const float* qp = q + base;
    const float* kp = k + base;

    for (int dc = 0; dc < HD; dc += CHUNK) {
        float qreg[CHUNK];
        float kreg[CHUNK][9];
        #pragma unroll
        for (int u = 0; u < CHUNK; ++u) {
            const float* kc = kp + (size_t)(dc + u) * PLANE;
            qreg[u] = qp[(size_t)(dc + u) * PLANE];
            #pragma unroll
            for (int n = 0; n < 9; ++n) kreg[u][n] = kc[off[n]];
        }
        #pragma unroll
        for (int u = 0; u < CHUNK; ++u) {
            #pragma unroll
            for (int n = 0; n < 9; ++n)
                s[n] = fmaf(qreg[u], kreg[u][n], s[n]);
        }
    }

    // Cancel garbage from clamped loads (zero-padded semantics: invalid tap
    // score is exactly 0 and still participates in the softmax denominator).
    #pragma unroll
    for (int n = 0; n < 9; ++n) if (!tv[n]) s[n] = 0.f;

    // ---- Softmax over 9 taps ----
    const float scale = 0.17677669529663687f;  // 32^-0.5
    float m = -3.4e38f;
    #pragma unroll
    for (int n = 0; n < 9; ++n) { s[n] *= scale; m = fmaxf(m, s[n]); }
    float sum = 0.f;
    #pragma unroll
    for (int n = 0; n < 9; ++n) { s[n] = __expf(s[n] - m); sum += s[n]; }
    const float inv = 1.f / sum;
    #pragma unroll
    for (int n = 0; n < 9; ++n) s[n] *= inv;

    // Zero weights of invalid taps (their v is zero-padded in the reference).
    #pragma unroll
    for (int n = 0; n < 9; ++n) if (!tv[n]) s[n] = 0.f;

    // ---- Pass 2: out. Same phase-split structure; NONTEMPORAL stores ----
    const float* vp = v + base;
    float*       op = out + base;

    for (int dc = 0; dc < HD; dc += CHUNK) {
        float vreg[CHUNK][9];
        #pragma unroll
        for (int u = 0; u < CHUNK; ++u) {
            const float* vc = vp + (size_t)(dc + u) * PLANE;
            #pragma unroll
            for (int n = 0; n < 9; ++n) vreg[u][n] = vc[off[n]];
        }
        #pragma unroll
        for (int u = 0; u < CHUNK; ++u) {
            float acc = 0.f;
            #pragma unroll
            for (int n = 0; n < 9; ++n)
                acc = fmaf(s[n], vreg[u][n], acc);
            __builtin_nontemporal_store(acc, op + (size_t)(dc + u) * PLANE);
        }
    }
}

extern "C" void kernel_launch(void* const* d_in, const int* in_sizes, int n_in,
                              void* d_out, int out_size, void* d_ws, size_t ws_size,
                              hipStream_t stream) {
    const float* q = (const float*)d_in[0];
    const float* k = (const float*)d_in[1];
    const float* v = (const float*)d_in[2];
    float* out = (float*)d_out;

    dim3 grid(BB * HH);   // 2048 blocks, one (b,h) row each
    dim3 block(WW);       // 128 threads = 2 waves
    dilate_attn_kernel<<<grid, block, 0, stream>>>(q, k, v, out);
}